// Round 4
// baseline (552.344 us; speedup 1.0000x reference)
//
#include <hip/hip_runtime.h>
#include <math.h>

#define N0 3190
#define NT 32768
#define E0 51040
#define CH 480   // x0 rows per LDS chunk (CH*13 floats = 24.4KB pool, >= 24KB merge)

// ws layout (floats):
// [0,N0)        n0
// [N0,2N0)      rn0 = 1/n0
// [2N0,12N0)    agg (N0*10)
// [12N0,13N0)   cnt
// [13N0,28N0)   o1_0 (N0*15)

__global__ void prep_x0(const float* __restrict__ x0, float* __restrict__ ws) {
    int i = blockIdx.x * 256 + threadIdx.x;
    if (i >= N0) return;
    float s = 0.f;
#pragma unroll
    for (int c = 0; c < 10; ++c) { float v = x0[i * 10 + c]; s = fmaf(v, v, s); }
    float n = sqrtf(s);
    ws[i] = n;
    ws[N0 + i] = 1.0f / n;
#pragma unroll
    for (int c = 0; c < 10; ++c) ws[2 * N0 + i * 10 + c] = 0.f;
    ws[12 * N0 + i] = 0.f;
}

__global__ void sage1_scatter(const float* __restrict__ x0, const int* __restrict__ e0,
                              float* __restrict__ ws) {
    int e = blockIdx.x * 256 + threadIdx.x;
    if (e >= E0) return;
    int s = e0[e];
    int d = e0[E0 + e];
    float* agg = ws + 2 * N0;
#pragma unroll
    for (int c = 0; c < 10; ++c) atomicAdd(&agg[d * 10 + c], x0[s * 10 + c]);
    atomicAdd(&ws[12 * N0 + d], 1.0f);
}

__global__ void sage1_finish(const float* __restrict__ x0,
                             const float* __restrict__ c1_wl, const float* __restrict__ c1_bl,
                             const float* __restrict__ c1_wr, float* __restrict__ ws) {
    int i = blockIdx.x * 256 + threadIdx.x;
    if (i >= N0) return;
    const float* agg = ws + 2 * N0 + i * 10;
    float den = fmaxf(ws[12 * N0 + i], 1.0f);
    float m[10], xr[10];
#pragma unroll
    for (int c = 0; c < 10; ++c) { m[c] = agg[c] / den; xr[c] = x0[i * 10 + c]; }
    float* o = ws + 13 * N0 + i * 15;
#pragma unroll
    for (int k = 0; k < 15; ++k) {
        float s = c1_bl[k];
#pragma unroll
        for (int c = 0; c < 10; ++c) s = fmaf(m[c], c1_wl[k * 10 + c], s);
#pragma unroll
        for (int c = 0; c < 10; ++c) s = fmaf(xr[c], c1_wr[k * 10 + c], s);
        o[k] = fmaxf(s, 0.f);
    }
}

// strict-> insertion (stable for ascending scan order)
__device__ __forceinline__ void ins6(float key, int jj,
    float& v0, float& v1, float& v2, float& v3, float& v4, float& v5,
    int& i0, int& i1, int& i2, int& i3, int& i4, int& i5) {
    if (key > v5) {
        if (key > v4) { v5 = v4; i5 = i4;
            if (key > v3) { v4 = v3; i4 = i3;
                if (key > v2) { v3 = v2; i3 = i2;
                    if (key > v1) { v2 = v1; i2 = i1;
                        if (key > v0) { v1 = v0; i1 = i0; v0 = key; i0 = jj; }
                        else { v1 = key; i1 = jj; }
                    } else { v2 = key; i2 = jj; }
                } else { v3 = key; i3 = jj; }
            } else { v4 = key; i4 = jj; }
        } else { v5 = key; i5 = jj; }
    }
}

#define BETTER(k, j, v, i) ((k) > (v) || ((k) == (v) && (j) < (i)))

// tie-aware insertion (for cross-lane merge)
__device__ __forceinline__ void ins6b(float kv, int ki,
    float& v0, float& v1, float& v2, float& v3, float& v4, float& v5,
    int& i0, int& i1, int& i2, int& i3, int& i4, int& i5) {
    if (BETTER(kv, ki, v5, i5)) {
        if (BETTER(kv, ki, v4, i4)) { v5 = v4; i5 = i4;
            if (BETTER(kv, ki, v3, i3)) { v4 = v3; i4 = i3;
                if (BETTER(kv, ki, v2, i2)) { v3 = v2; i3 = i2;
                    if (BETTER(kv, ki, v1, i1)) { v2 = v1; i2 = i1;
                        if (BETTER(kv, ki, v0, i0)) { v1 = v0; i1 = i0; v0 = kv; i0 = ki; }
                        else { v1 = kv; i1 = ki; }
                    } else { v2 = kv; i2 = ki; }
                } else { v3 = kv; i3 = ki; }
            } else { v4 = kv; i4 = ki; }
        } else { v5 = kv; i5 = ki; }
    }
}

__launch_bounds__(256)
__attribute__((amdgpu_waves_per_eu(2, 4)))
__global__ void main_kernel(const float* __restrict__ x, const float* __restrict__ x0,
                            const float* __restrict__ emb_w, const float* __restrict__ fc_w,
                            const float* __restrict__ fc_b, const float* __restrict__ fc2_w,
                            const float* __restrict__ fc2_b,
                            const float* __restrict__ c1_wr, const float* __restrict__ c1_bl,
                            const float* __restrict__ c2_wl, const float* __restrict__ c2_bl,
                            const float* __restrict__ c2_wr,
                            const float* __restrict__ lin_w, const float* __restrict__ lin_b,
                            const float* __restrict__ ws, float* __restrict__ out) {
    __shared__ float s_emb[25], s_fcw[1200], s_fcb[20], s_fc2w[1000], s_fc2b[10];
    __shared__ float s_c1wr[150], s_c1bl[15], s_c2wl[150], s_c2bl[10], s_c2wr[150];
    __shared__ float s_linw[30], s_linb[3];
    __shared__ __align__(16) float s_pool[CH * 13];   // x0 chunk (CH*12) + rn0 (CH); aliased by merge lists
    __shared__ __align__(16) float s_h[64 * 12];
    __shared__ float s_nh[64];

    float* s_x0  = s_pool;
    float* s_rn0 = s_pool + CH * 12;
    float* s_mv  = s_pool;                 // 64*48 = 3072 floats
    int*   s_mi  = (int*)(s_pool + 64 * 48);

    const int tid = threadIdx.x;
    for (int i = tid; i < 25;   i += 256) s_emb[i]  = emb_w[i];
    for (int i = tid; i < 1200; i += 256) s_fcw[i]  = fc_w[i];
    for (int i = tid; i < 20;   i += 256) s_fcb[i]  = fc_b[i];
    for (int i = tid; i < 1000; i += 256) s_fc2w[i] = fc2_w[i];
    for (int i = tid; i < 10;   i += 256) s_fc2b[i] = fc2_b[i];
    for (int i = tid; i < 150;  i += 256) s_c1wr[i] = c1_wr[i];
    for (int i = tid; i < 15;   i += 256) s_c1bl[i] = c1_bl[i];
    for (int i = tid; i < 150;  i += 256) s_c2wl[i] = c2_wl[i];
    for (int i = tid; i < 10;   i += 256) s_c2bl[i] = c2_bl[i];
    for (int i = tid; i < 150;  i += 256) s_c2wr[i] = c2_wr[i];
    for (int i = tid; i < 30;   i += 256) s_linw[i] = lin_w[i];
    for (int i = tid; i < 3;    i += 256) s_linb[i] = lin_b[i];
    __syncthreads();

    // ---------- encoder: 4 lanes per node, k-quarter split ----------
    const int nl_e = tid >> 2;           // block-local node 0..63
    const int q = tid & 3;
    const int node = blockIdx.x * 64 + nl_e;

    float acc[5][5];   // [e][kl], k = 5*q+kl
#pragma unroll
    for (int e = 0; e < 5; ++e)
#pragma unroll
        for (int kl = 0; kl < 5; ++kl) acc[e][kl] = 0.f;

    const float* xp = x + (size_t)node * 5;
    for (int f = 0; f < 60; ++f) {
        float xin[5];
#pragma unroll
        for (int c = 0; c < 5; ++c) xin[c] = xp[(size_t)f * NT * 5 + c];
        float hm[5];
#pragma unroll
        for (int e = 0; e < 5; ++e) {
            float s = 0.f;
#pragma unroll
            for (int c = 0; c < 5; ++c) s = fmaf(xin[c], s_emb[c * 5 + e], s);
            hm[e] = fmaxf(s, 0.f);
        }
#pragma unroll
        for (int kl = 0; kl < 5; ++kl) {
            float w = s_fcw[(5 * q + kl) * 60 + f];
#pragma unroll
            for (int e = 0; e < 5; ++e) acc[e][kl] = fmaf(hm[e], w, acc[e][kl]);
        }
    }

    float hp[10];
#pragma unroll
    for (int u = 0; u < 10; ++u) hp[u] = 0.f;
#pragma unroll
    for (int kl = 0; kl < 5; ++kl) {
        const int k = 5 * q + kl;
#pragma unroll
        for (int e = 0; e < 5; ++e) {
            float z = fmaxf(acc[e][kl] + s_fcb[k], 0.f);
            const int zi = k * 5 + e;
#pragma unroll
            for (int u = 0; u < 10; ++u) hp[u] = fmaf(s_fc2w[u * 100 + zi], z, hp[u]);
        }
    }
#pragma unroll
    for (int u = 0; u < 10; ++u) {
        hp[u] += __shfl_xor(hp[u], 1);
        hp[u] += __shfl_xor(hp[u], 2);
    }
    float hv[10];
#pragma unroll
    for (int u = 0; u < 10; ++u) hv[u] = fmaxf(hp[u] + s_fc2b[u], 0.f);

    if (q == 0) {
        float nh2 = 0.f;
#pragma unroll
        for (int u = 0; u < 10; ++u) { s_h[nl_e * 12 + u] = hv[u]; nh2 = fmaf(hv[u], hv[u], nh2); }
        s_nh[nl_e] = sqrtf(nh2);
    }
    __syncthreads();

    // ---------- cos scan: 2 nodes/thread, 8 lanes/pair ----------
    const int pp = tid >> 3;             // pair 0..31  (nodes 2pp, 2pp+1)
    const int l  = tid & 7;
    float hA[10], hB[10];
#pragma unroll
    for (int u = 0; u < 10; ++u) {
        hA[u] = s_h[(2 * pp) * 12 + u];
        hB[u] = s_h[(2 * pp + 1) * 12 + u];
    }

    float av0 = -INFINITY, av1 = -INFINITY, av2 = -INFINITY, av3 = -INFINITY, av4 = -INFINITY, av5 = -INFINITY;
    int   ai0 = 0, ai1 = 0, ai2 = 0, ai3 = 0, ai4 = 0, ai5 = 0;
    float bv0 = -INFINITY, bv1 = -INFINITY, bv2 = -INFINITY, bv3 = -INFINITY, bv4 = -INFINITY, bv5 = -INFINITY;
    int   bi0 = 0, bi1 = 0, bi2 = 0, bi3 = 0, bi4 = 0, bi5 = 0;

    for (int c0 = 0; c0 < N0; c0 += CH) {
        const int cn = min(CH, N0 - c0);
        __syncthreads();
        for (int idx = tid; idx < cn * 10; idx += 256) {
            int r = idx / 10;
            int cc = idx - r * 10;
            s_x0[r * 12 + cc] = x0[(size_t)(c0 + r) * 10 + cc];
        }
        for (int idx = tid; idx < cn; idx += 256) s_rn0[idx] = ws[N0 + c0 + idx];
        __syncthreads();

        int j = l;
        for (; j + 8 < cn; j += 16) {
            const float* r0p = s_x0 + j * 12;
            const float* r1p = s_x0 + (j + 8) * 12;
            float4 p0 = *(const float4*)r0p;
            float4 p1 = *(const float4*)(r0p + 4);
            float2 p2 = *(const float2*)(r0p + 8);
            float  rn0v = s_rn0[j];
            float4 q0 = *(const float4*)r1p;
            float4 q1 = *(const float4*)(r1p + 4);
            float2 q2 = *(const float2*)(r1p + 8);
            float  rn1v = s_rn0[j + 8];

            float dA0 = 0.f, dB0 = 0.f, dA1 = 0.f, dB1 = 0.f;
            dA0 = fmaf(hA[0], p0.x, dA0); dA0 = fmaf(hA[1], p0.y, dA0); dA0 = fmaf(hA[2], p0.z, dA0); dA0 = fmaf(hA[3], p0.w, dA0);
            dA0 = fmaf(hA[4], p1.x, dA0); dA0 = fmaf(hA[5], p1.y, dA0); dA0 = fmaf(hA[6], p1.z, dA0); dA0 = fmaf(hA[7], p1.w, dA0);
            dA0 = fmaf(hA[8], p2.x, dA0); dA0 = fmaf(hA[9], p2.y, dA0);
            dB0 = fmaf(hB[0], p0.x, dB0); dB0 = fmaf(hB[1], p0.y, dB0); dB0 = fmaf(hB[2], p0.z, dB0); dB0 = fmaf(hB[3], p0.w, dB0);
            dB0 = fmaf(hB[4], p1.x, dB0); dB0 = fmaf(hB[5], p1.y, dB0); dB0 = fmaf(hB[6], p1.z, dB0); dB0 = fmaf(hB[7], p1.w, dB0);
            dB0 = fmaf(hB[8], p2.x, dB0); dB0 = fmaf(hB[9], p2.y, dB0);
            dA1 = fmaf(hA[0], q0.x, dA1); dA1 = fmaf(hA[1], q0.y, dA1); dA1 = fmaf(hA[2], q0.z, dA1); dA1 = fmaf(hA[3], q0.w, dA1);
            dA1 = fmaf(hA[4], q1.x, dA1); dA1 = fmaf(hA[5], q1.y, dA1); dA1 = fmaf(hA[6], q1.z, dA1); dA1 = fmaf(hA[7], q1.w, dA1);
            dA1 = fmaf(hA[8], q2.x, dA1); dA1 = fmaf(hA[9], q2.y, dA1);
            dB1 = fmaf(hB[0], q0.x, dB1); dB1 = fmaf(hB[1], q0.y, dB1); dB1 = fmaf(hB[2], q0.z, dB1); dB1 = fmaf(hB[3], q0.w, dB1);
            dB1 = fmaf(hB[4], q1.x, dB1); dB1 = fmaf(hB[5], q1.y, dB1); dB1 = fmaf(hB[6], q1.z, dB1); dB1 = fmaf(hB[7], q1.w, dB1);
            dB1 = fmaf(hB[8], q2.x, dB1); dB1 = fmaf(hB[9], q2.y, dB1);

            ins6(dA0 * rn0v, c0 + j, av0, av1, av2, av3, av4, av5, ai0, ai1, ai2, ai3, ai4, ai5);
            ins6(dB0 * rn0v, c0 + j, bv0, bv1, bv2, bv3, bv4, bv5, bi0, bi1, bi2, bi3, bi4, bi5);
            ins6(dA1 * rn1v, c0 + j + 8, av0, av1, av2, av3, av4, av5, ai0, ai1, ai2, ai3, ai4, ai5);
            ins6(dB1 * rn1v, c0 + j + 8, bv0, bv1, bv2, bv3, bv4, bv5, bi0, bi1, bi2, bi3, bi4, bi5);
        }
        if (j < cn) {
            const float* r0p = s_x0 + j * 12;
            float4 p0 = *(const float4*)r0p;
            float4 p1 = *(const float4*)(r0p + 4);
            float2 p2 = *(const float2*)(r0p + 8);
            float  rn0v = s_rn0[j];
            float dA0 = 0.f, dB0 = 0.f;
            dA0 = fmaf(hA[0], p0.x, dA0); dA0 = fmaf(hA[1], p0.y, dA0); dA0 = fmaf(hA[2], p0.z, dA0); dA0 = fmaf(hA[3], p0.w, dA0);
            dA0 = fmaf(hA[4], p1.x, dA0); dA0 = fmaf(hA[5], p1.y, dA0); dA0 = fmaf(hA[6], p1.z, dA0); dA0 = fmaf(hA[7], p1.w, dA0);
            dA0 = fmaf(hA[8], p2.x, dA0); dA0 = fmaf(hA[9], p2.y, dA0);
            dB0 = fmaf(hB[0], p0.x, dB0); dB0 = fmaf(hB[1], p0.y, dB0); dB0 = fmaf(hB[2], p0.z, dB0); dB0 = fmaf(hB[3], p0.w, dB0);
            dB0 = fmaf(hB[4], p1.x, dB0); dB0 = fmaf(hB[5], p1.y, dB0); dB0 = fmaf(hB[6], p1.z, dB0); dB0 = fmaf(hB[7], p1.w, dB0);
            dB0 = fmaf(hB[8], p2.x, dB0); dB0 = fmaf(hB[9], p2.y, dB0);
            ins6(dA0 * rn0v, c0 + j, av0, av1, av2, av3, av4, av5, ai0, ai1, ai2, ai3, ai4, ai5);
            ins6(dB0 * rn0v, c0 + j, bv0, bv1, bv2, bv3, bv4, bv5, bi0, bi1, bi2, bi3, bi4, bi5);
        }
    }

    // ---------- merge: 8 lanes x top-6 per node, via aliased LDS ----------
    __syncthreads();   // all scans done; safe to overwrite s_x0/s_rn0
    {
        int ba = (2 * pp) * 48 + l * 6;
        s_mv[ba + 0] = av0; s_mi[ba + 0] = ai0;
        s_mv[ba + 1] = av1; s_mi[ba + 1] = ai1;
        s_mv[ba + 2] = av2; s_mi[ba + 2] = ai2;
        s_mv[ba + 3] = av3; s_mi[ba + 3] = ai3;
        s_mv[ba + 4] = av4; s_mi[ba + 4] = ai4;
        s_mv[ba + 5] = av5; s_mi[ba + 5] = ai5;
        int bb = (2 * pp + 1) * 48 + l * 6;
        s_mv[bb + 0] = bv0; s_mi[bb + 0] = bi0;
        s_mv[bb + 1] = bv1; s_mi[bb + 1] = bi1;
        s_mv[bb + 2] = bv2; s_mi[bb + 2] = bi2;
        s_mv[bb + 3] = bv3; s_mi[bb + 3] = bi3;
        s_mv[bb + 4] = bv4; s_mi[bb + 4] = bi4;
        s_mv[bb + 5] = bv5; s_mi[bb + 5] = bi5;
    }
    __syncthreads();

    if (tid < 64) {
        const int nl = tid;
        float m0 = -INFINITY, m1 = -INFINITY, m2 = -INFINITY, m3 = -INFINITY, m4 = -INFINITY, m5 = -INFINITY;
        int j0 = 0, j1 = 0, j2 = 0, j3 = 0, j4 = 0, j5 = 0;
        const float* mv = s_mv + nl * 48;
        const int*   mi = s_mi + nl * 48;
        for (int s = 0; s < 48; ++s)
            ins6b(mv[s], mi[s], m0, m1, m2, m3, m4, m5, j0, j1, j2, j3, j4, j5);

        float h[10];
#pragma unroll
        for (int u = 0; u < 10; ++u) h[u] = s_h[nl * 12 + u];
        const float nh = s_nh[nl];

        // SAGE1 at test node (no incoming base edges -> agg = 0)
        float o1t[15];
#pragma unroll
        for (int k = 0; k < 15; ++k) {
            float s = s_c1bl[k];
#pragma unroll
            for (int u = 0; u < 10; ++u) s = fmaf(h[u], s_c1wr[k * 10 + u], s);
            o1t[k] = fmaxf(s, 0.f);
        }

        // selfmatch: recompute exact a = (dot/nh)/n0 for the top entry
        float dot0 = 0.f;
        const float* xr = x0 + (size_t)j0 * 10;
#pragma unroll
        for (int c = 0; c < 10; ++c) dot0 = fmaf(h[c], xr[c], dot0);
        float a0 = (dot0 / nh) / ws[j0];
        bool selfm = (a0 == 1.0f);
        int n1 = selfm ? j1 : j0;
        int n2 = selfm ? j2 : j1;
        int n3 = selfm ? j3 : j2;
        int n4 = selfm ? j4 : j3;
        int n5 = selfm ? j5 : j4;

        const float* o10 = ws + 13 * N0;
        float mean[15];
#pragma unroll
        for (int k = 0; k < 15; ++k) {
            float s = o10[(size_t)n1 * 15 + k];
            s += o10[(size_t)n2 * 15 + k];
            s += o10[(size_t)n3 * 15 + k];
            s += o10[(size_t)n4 * 15 + k];
            s += o10[(size_t)n5 * 15 + k];
            mean[k] = s / 5.0f;
        }

        float o2[10];
#pragma unroll
        for (int u = 0; u < 10; ++u) {
            float s = s_c2bl[u];
#pragma unroll
            for (int k = 0; k < 15; ++k) s = fmaf(mean[k], s_c2wl[u * 15 + k], s);
#pragma unroll
            for (int k = 0; k < 15; ++k) s = fmaf(o1t[k], s_c2wr[u * 15 + k], s);
            o2[u] = s;
        }

        float l0 = s_linb[0], l1 = s_linb[1], l2 = s_linb[2];
#pragma unroll
        for (int u = 0; u < 10; ++u) {
            l0 = fmaf(o2[u], s_linw[u], l0);
            l1 = fmaf(o2[u], s_linw[10 + u], l1);
            l2 = fmaf(o2[u], s_linw[20 + u], l2);
        }
        float mx = fmaxf(l0, fmaxf(l1, l2));
        float e0 = expf(l0 - mx), e1 = expf(l1 - mx), e2 = expf(l2 - mx);
        float sum = e0 + e1 + e2;
        const int gnode = blockIdx.x * 64 + nl;
        out[(size_t)gnode * 3 + 0] = e0 / sum;
        out[(size_t)gnode * 3 + 1] = e1 / sum;
        out[(size_t)gnode * 3 + 2] = e2 / sum;
    }
}

extern "C" void kernel_launch(void* const* d_in, const int* in_sizes, int n_in,
                              void* d_out, int out_size, void* d_ws, size_t ws_size,
                              hipStream_t stream) {
    const float* x     = (const float*)d_in[0];
    const float* x0    = (const float*)d_in[1];
    const int*   e0    = (const int*)d_in[2];
    const float* emb_w = (const float*)d_in[3];
    const float* fc_w  = (const float*)d_in[4];
    const float* fc_b  = (const float*)d_in[5];
    const float* fc2_w = (const float*)d_in[6];
    const float* fc2_b = (const float*)d_in[7];
    const float* c1_wl = (const float*)d_in[8];
    const float* c1_bl = (const float*)d_in[9];
    const float* c1_wr = (const float*)d_in[10];
    const float* c2_wl = (const float*)d_in[11];
    const float* c2_bl = (const float*)d_in[12];
    const float* c2_wr = (const float*)d_in[13];
    const float* lin_w = (const float*)d_in[14];
    const float* lin_b = (const float*)d_in[15];
    float* ws  = (float*)d_ws;
    float* out = (float*)d_out;

    prep_x0<<<(N0 + 255) / 256, 256, 0, stream>>>(x0, ws);
    sage1_scatter<<<(E0 + 255) / 256, 256, 0, stream>>>(x0, e0, ws);
    sage1_finish<<<(N0 + 255) / 256, 256, 0, stream>>>(x0, c1_wl, c1_bl, c1_wr, ws);
    main_kernel<<<NT / 64, 256, 0, stream>>>(x, x0, emb_w, fc_w, fc_b, fc2_w, fc2_b,
                                             c1_wr, c1_bl, c2_wl, c2_bl, c2_wr,
                                             lin_w, lin_b, ws, out);
}

// Round 5
// 359.074 us; speedup vs baseline: 1.5382x; 1.5382x over previous
//
#include <hip/hip_runtime.h>
#include <math.h>

#define N0 3190
#define NT 32768
#define E0 51040
#define CH 512   // x0 rows per LDS chunk

// ws layout (floats):
// [0,N0)        n0
// [N0,2N0)      rn0 = 1/n0
// [2N0,12N0)    agg (N0*10)
// [12N0,13N0)   cnt
// [13N0,28N0)   o1_0 (N0*15)

__global__ void prep_x0(const float* __restrict__ x0, float* __restrict__ ws) {
    int i = blockIdx.x * 256 + threadIdx.x;
    if (i >= N0) return;
    float s = 0.f;
#pragma unroll
    for (int c = 0; c < 10; ++c) { float v = x0[i * 10 + c]; s = fmaf(v, v, s); }
    float n = sqrtf(s);
    ws[i] = n;
    ws[N0 + i] = 1.0f / n;
#pragma unroll
    for (int c = 0; c < 10; ++c) ws[2 * N0 + i * 10 + c] = 0.f;
    ws[12 * N0 + i] = 0.f;
}

__global__ void sage1_scatter(const float* __restrict__ x0, const int* __restrict__ e0,
                              float* __restrict__ ws) {
    int e = blockIdx.x * 256 + threadIdx.x;
    if (e >= E0) return;
    int s = e0[e];
    int d = e0[E0 + e];
    float* agg = ws + 2 * N0;
#pragma unroll
    for (int c = 0; c < 10; ++c) atomicAdd(&agg[d * 10 + c], x0[s * 10 + c]);
    atomicAdd(&ws[12 * N0 + d], 1.0f);
}

__global__ void sage1_finish(const float* __restrict__ x0,
                             const float* __restrict__ c1_wl, const float* __restrict__ c1_bl,
                             const float* __restrict__ c1_wr, float* __restrict__ ws) {
    int i = blockIdx.x * 256 + threadIdx.x;
    if (i >= N0) return;
    const float* agg = ws + 2 * N0 + i * 10;
    float den = fmaxf(ws[12 * N0 + i], 1.0f);
    float m[10], xr[10];
#pragma unroll
    for (int c = 0; c < 10; ++c) { m[c] = agg[c] / den; xr[c] = x0[i * 10 + c]; }
    float* o = ws + 13 * N0 + i * 15;
#pragma unroll
    for (int k = 0; k < 15; ++k) {
        float s = c1_bl[k];
#pragma unroll
        for (int c = 0; c < 10; ++c) s = fmaf(m[c], c1_wl[k * 10 + c], s);
#pragma unroll
        for (int c = 0; c < 10; ++c) s = fmaf(xr[c], c1_wr[k * 10 + c], s);
        o[k] = fmaxf(s, 0.f);
    }
}

// strict-> insertion (stable for ascending scan order)
__device__ __forceinline__ void ins6(float key, int jj,
    float& v0, float& v1, float& v2, float& v3, float& v4, float& v5,
    int& i0, int& i1, int& i2, int& i3, int& i4, int& i5) {
    if (key > v5) {
        if (key > v4) { v5 = v4; i5 = i4;
            if (key > v3) { v4 = v3; i4 = i3;
                if (key > v2) { v3 = v2; i3 = i2;
                    if (key > v1) { v2 = v1; i2 = i1;
                        if (key > v0) { v1 = v0; i1 = i0; v0 = key; i0 = jj; }
                        else { v1 = key; i1 = jj; }
                    } else { v2 = key; i2 = jj; }
                } else { v3 = key; i3 = jj; }
            } else { v4 = key; i4 = jj; }
        } else { v5 = key; i5 = jj; }
    }
}

#define BETTER(k, j, v, i) ((k) > (v) || ((k) == (v) && (j) < (i)))

// tie-aware insertion (for cross-lane merge)
__device__ __forceinline__ void ins6b(float kv, int ki,
    float& v0, float& v1, float& v2, float& v3, float& v4, float& v5,
    int& i0, int& i1, int& i2, int& i3, int& i4, int& i5) {
    if (BETTER(kv, ki, v5, i5)) {
        if (BETTER(kv, ki, v4, i4)) { v5 = v4; i5 = i4;
            if (BETTER(kv, ki, v3, i3)) { v4 = v3; i4 = i3;
                if (BETTER(kv, ki, v2, i2)) { v3 = v2; i3 = i2;
                    if (BETTER(kv, ki, v1, i1)) { v2 = v1; i2 = i1;
                        if (BETTER(kv, ki, v0, i0)) { v1 = v0; i1 = i0; v0 = kv; i0 = ki; }
                        else { v1 = kv; i1 = ki; }
                    } else { v2 = kv; i2 = ki; }
                } else { v3 = kv; i3 = ki; }
            } else { v4 = kv; i4 = ki; }
        } else { v5 = kv; i5 = ki; }
    }
}

__launch_bounds__(256, 1)
__global__ void main_kernel(const float* __restrict__ x, const float* __restrict__ x0,
                            const float* __restrict__ emb_w, const float* __restrict__ fc_w,
                            const float* __restrict__ fc_b, const float* __restrict__ fc2_w,
                            const float* __restrict__ fc2_b,
                            const float* __restrict__ c1_wr, const float* __restrict__ c1_bl,
                            const float* __restrict__ c2_wl, const float* __restrict__ c2_bl,
                            const float* __restrict__ c2_wr,
                            const float* __restrict__ lin_w, const float* __restrict__ lin_b,
                            const float* __restrict__ ws, float* __restrict__ out) {
    __shared__ float s_emb[25], s_fcw[1200], s_fcb[20], s_fc2w[1000], s_fc2b[10];
    __shared__ float s_c1wr[150], s_c1bl[15], s_c2wl[150], s_c2bl[10], s_c2wr[150];
    __shared__ float s_linw[30], s_linb[3];
    __shared__ __align__(16) float s_x0[CH * 12];   // cols 0-9: x0 row; col 10: rn0; col 11: pad
    __shared__ float s_mv[64 * 24];
    __shared__ int   s_mi[64 * 24];

    const int tid = threadIdx.x;
    for (int i = tid; i < 25;   i += 256) s_emb[i]  = emb_w[i];
    for (int i = tid; i < 1200; i += 256) s_fcw[i]  = fc_w[i];
    for (int i = tid; i < 20;   i += 256) s_fcb[i]  = fc_b[i];
    for (int i = tid; i < 1000; i += 256) s_fc2w[i] = fc2_w[i];
    for (int i = tid; i < 10;   i += 256) s_fc2b[i] = fc2_b[i];
    for (int i = tid; i < 150;  i += 256) s_c1wr[i] = c1_wr[i];
    for (int i = tid; i < 15;   i += 256) s_c1bl[i] = c1_bl[i];
    for (int i = tid; i < 150;  i += 256) s_c2wl[i] = c2_wl[i];
    for (int i = tid; i < 10;   i += 256) s_c2bl[i] = c2_bl[i];
    for (int i = tid; i < 150;  i += 256) s_c2wr[i] = c2_wr[i];
    for (int i = tid; i < 30;   i += 256) s_linw[i] = lin_w[i];
    for (int i = tid; i < 3;    i += 256) s_linb[i] = lin_b[i];
    __syncthreads();

    const int node = blockIdx.x * 64 + (tid >> 2);
    const int q = tid & 3;

    // ---------- encoder (k-quarter per lane) ----------
    float acc[5][5];   // [e][kl], k = 5*q+kl
#pragma unroll
    for (int e = 0; e < 5; ++e)
#pragma unroll
        for (int kl = 0; kl < 5; ++kl) acc[e][kl] = 0.f;

    const float* xp = x + (size_t)node * 5;
    for (int f = 0; f < 60; ++f) {
        float xin[5];
#pragma unroll
        for (int c = 0; c < 5; ++c) xin[c] = xp[(size_t)f * NT * 5 + c];
        float hm[5];
#pragma unroll
        for (int e = 0; e < 5; ++e) {
            float s = 0.f;
#pragma unroll
            for (int c = 0; c < 5; ++c) s = fmaf(xin[c], s_emb[c * 5 + e], s);
            hm[e] = fmaxf(s, 0.f);
        }
#pragma unroll
        for (int kl = 0; kl < 5; ++kl) {
            float w = s_fcw[(5 * q + kl) * 60 + f];
#pragma unroll
            for (int e = 0; e < 5; ++e) acc[e][kl] = fmaf(hm[e], w, acc[e][kl]);
        }
    }

    float hp[10];
#pragma unroll
    for (int u = 0; u < 10; ++u) hp[u] = 0.f;
#pragma unroll
    for (int kl = 0; kl < 5; ++kl) {
        const int k = 5 * q + kl;
#pragma unroll
        for (int e = 0; e < 5; ++e) {
            float z = fmaxf(acc[e][kl] + s_fcb[k], 0.f);
            const int zi = k * 5 + e;
#pragma unroll
            for (int u = 0; u < 10; ++u) hp[u] = fmaf(s_fc2w[u * 100 + zi], z, hp[u]);
        }
    }
#pragma unroll
    for (int u = 0; u < 10; ++u) {
        hp[u] += __shfl_xor(hp[u], 1);
        hp[u] += __shfl_xor(hp[u], 2);
    }
    float h[10];
#pragma unroll
    for (int u = 0; u < 10; ++u) h[u] = fmaxf(hp[u] + s_fc2b[u], 0.f);

    float nh2 = 0.f;
#pragma unroll
    for (int u = 0; u < 10; ++u) nh2 = fmaf(h[u], h[u], nh2);
    const float nh = sqrtf(nh2);

    // SAGE1 at test node: no incoming edge_0 edges -> agg=0
    float o1t[15];
#pragma unroll
    for (int k = 0; k < 15; ++k) {
        float s = s_c1bl[k];
#pragma unroll
        for (int u = 0; u < 10; ++u) s = fmaf(h[u], s_c1wr[k * 10 + u], s);
        o1t[k] = fmaxf(s, 0.f);
    }

    // ---------- cosine top-6 (stable), j strided by quad lane, 2-row unroll ----------
    float v0 = -INFINITY, v1 = -INFINITY, v2 = -INFINITY, v3 = -INFINITY, v4 = -INFINITY, v5 = -INFINITY;
    int i0 = 0, i1 = 0, i2 = 0, i3 = 0, i4 = 0, i5 = 0;

    for (int c0 = 0; c0 < N0; c0 += CH) {
        const int cn = min(CH, N0 - c0);
        __syncthreads();
        for (int idx = tid; idx < cn * 10; idx += 256) {
            int r = idx / 10;
            int cc = idx - r * 10;
            s_x0[r * 12 + cc] = x0[(size_t)(c0 + r) * 10 + cc];
        }
        for (int idx = tid; idx < cn; idx += 256) s_x0[idx * 12 + 10] = ws[N0 + c0 + idx];
        __syncthreads();

        int j = q;
        for (; j + 4 < cn; j += 8) {
            const float* r0p = s_x0 + j * 12;
            const float* r1p = s_x0 + (j + 4) * 12;
            float4 p0 = *(const float4*)r0p;
            float4 p1 = *(const float4*)(r0p + 4);
            float4 p2 = *(const float4*)(r0p + 8);   // x,y = data[8..9], z = rn0
            float4 g0 = *(const float4*)r1p;
            float4 g1 = *(const float4*)(r1p + 4);
            float4 g2 = *(const float4*)(r1p + 8);

            float dA = 0.f, dB = 0.f;
            dA = fmaf(h[0], p0.x, dA); dA = fmaf(h[1], p0.y, dA); dA = fmaf(h[2], p0.z, dA); dA = fmaf(h[3], p0.w, dA);
            dA = fmaf(h[4], p1.x, dA); dA = fmaf(h[5], p1.y, dA); dA = fmaf(h[6], p1.z, dA); dA = fmaf(h[7], p1.w, dA);
            dA = fmaf(h[8], p2.x, dA); dA = fmaf(h[9], p2.y, dA);
            dB = fmaf(h[0], g0.x, dB); dB = fmaf(h[1], g0.y, dB); dB = fmaf(h[2], g0.z, dB); dB = fmaf(h[3], g0.w, dB);
            dB = fmaf(h[4], g1.x, dB); dB = fmaf(h[5], g1.y, dB); dB = fmaf(h[6], g1.z, dB); dB = fmaf(h[7], g1.w, dB);
            dB = fmaf(h[8], g2.x, dB); dB = fmaf(h[9], g2.y, dB);

            ins6(dA * p2.z, c0 + j,     v0, v1, v2, v3, v4, v5, i0, i1, i2, i3, i4, i5);
            ins6(dB * g2.z, c0 + j + 4, v0, v1, v2, v3, v4, v5, i0, i1, i2, i3, i4, i5);
        }
        if (j < cn) {
            const float* r0p = s_x0 + j * 12;
            float4 p0 = *(const float4*)r0p;
            float4 p1 = *(const float4*)(r0p + 4);
            float4 p2 = *(const float4*)(r0p + 8);
            float dA = 0.f;
            dA = fmaf(h[0], p0.x, dA); dA = fmaf(h[1], p0.y, dA); dA = fmaf(h[2], p0.z, dA); dA = fmaf(h[3], p0.w, dA);
            dA = fmaf(h[4], p1.x, dA); dA = fmaf(h[5], p1.y, dA); dA = fmaf(h[6], p1.z, dA); dA = fmaf(h[7], p1.w, dA);
            dA = fmaf(h[8], p2.x, dA); dA = fmaf(h[9], p2.y, dA);
            ins6(dA * p2.z, c0 + j, v0, v1, v2, v3, v4, v5, i0, i1, i2, i3, i4, i5);
        }
    }

    // ---------- merge 4 lanes' top-6 -> global stable top-6 ----------
    const int nl = tid >> 2;
    {
        int b = nl * 24 + q * 6;
        s_mv[b + 0] = v0; s_mi[b + 0] = i0;
        s_mv[b + 1] = v1; s_mi[b + 1] = i1;
        s_mv[b + 2] = v2; s_mi[b + 2] = i2;
        s_mv[b + 3] = v3; s_mi[b + 3] = i3;
        s_mv[b + 4] = v4; s_mi[b + 4] = i4;
        s_mv[b + 5] = v5; s_mi[b + 5] = i5;
    }
    __syncthreads();

    if (q == 0) {
        float m0 = -INFINITY, m1 = -INFINITY, m2 = -INFINITY, m3 = -INFINITY, m4 = -INFINITY, m5 = -INFINITY;
        int j0 = 0, j1 = 0, j2 = 0, j3 = 0, j4 = 0, j5 = 0;
        for (int s = 0; s < 24; ++s) {
            float kv = s_mv[nl * 24 + s];
            int ki = s_mi[nl * 24 + s];
            if (BETTER(kv, ki, m5, j5)) {
                if (BETTER(kv, ki, m4, j4)) { m5 = m4; j5 = j4;
                    if (BETTER(kv, ki, m3, j3)) { m4 = m3; j4 = j3;
                        if (BETTER(kv, ki, m2, j2)) { m3 = m2; j3 = j2;
                            if (BETTER(kv, ki, m1, j1)) { m2 = m1; j2 = j1;
                                if (BETTER(kv, ki, m0, j0)) { m1 = m0; j1 = j0; m0 = kv; j0 = ki; }
                                else { m1 = kv; j1 = ki; }
                            } else { m2 = kv; j2 = ki; }
                        } else { m3 = kv; j3 = ki; }
                    } else { m4 = kv; j4 = ki; }
                } else { m5 = kv; j5 = ki; }
            }
        }

        // selfmatch: recompute exact a = (dot/nh)/n0 for the top entry
        float dot0 = 0.f;
        const float* xr = x0 + (size_t)j0 * 10;
#pragma unroll
        for (int c = 0; c < 10; ++c) dot0 = fmaf(h[c], xr[c], dot0);
        float a0 = (dot0 / nh) / ws[j0];
        bool selfm = (a0 == 1.0f);
        int n1 = selfm ? j1 : j0;
        int n2 = selfm ? j2 : j1;
        int n3 = selfm ? j3 : j2;
        int n4 = selfm ? j4 : j3;
        int n5 = selfm ? j5 : j4;

        const float* o10 = ws + 13 * N0;
        float mean[15];
#pragma unroll
        for (int k = 0; k < 15; ++k) {
            float s = o10[(size_t)n1 * 15 + k];
            s += o10[(size_t)n2 * 15 + k];
            s += o10[(size_t)n3 * 15 + k];
            s += o10[(size_t)n4 * 15 + k];
            s += o10[(size_t)n5 * 15 + k];
            mean[k] = s / 5.0f;
        }

        float o2[10];
#pragma unroll
        for (int u = 0; u < 10; ++u) {
            float s = s_c2bl[u];
#pragma unroll
            for (int k = 0; k < 15; ++k) s = fmaf(mean[k], s_c2wl[u * 15 + k], s);
#pragma unroll
            for (int k = 0; k < 15; ++k) s = fmaf(o1t[k], s_c2wr[u * 15 + k], s);
            o2[u] = s;
        }

        float l0 = s_linb[0], l1 = s_linb[1], l2 = s_linb[2];
#pragma unroll
        for (int u = 0; u < 10; ++u) {
            l0 = fmaf(o2[u], s_linw[u], l0);
            l1 = fmaf(o2[u], s_linw[10 + u], l1);
            l2 = fmaf(o2[u], s_linw[20 + u], l2);
        }
        float mx = fmaxf(l0, fmaxf(l1, l2));
        float e0 = expf(l0 - mx), e1 = expf(l1 - mx), e2 = expf(l2 - mx);
        float sum = e0 + e1 + e2;
        out[(size_t)node * 3 + 0] = e0 / sum;
        out[(size_t)node * 3 + 1] = e1 / sum;
        out[(size_t)node * 3 + 2] = e2 / sum;
    }
}

extern "C" void kernel_launch(void* const* d_in, const int* in_sizes, int n_in,
                              void* d_out, int out_size, void* d_ws, size_t ws_size,
                              hipStream_t stream) {
    const float* x     = (const float*)d_in[0];
    const float* x0    = (const float*)d_in[1];
    const int*   e0    = (const int*)d_in[2];
    const float* emb_w = (const float*)d_in[3];
    const float* fc_w  = (const float*)d_in[4];
    const float* fc_b  = (const float*)d_in[5];
    const float* fc2_w = (const float*)d_in[6];
    const float* fc2_b = (const float*)d_in[7];
    const float* c1_wl = (const float*)d_in[8];
    const float* c1_bl = (const float*)d_in[9];
    const float* c1_wr = (const float*)d_in[10];
    const float* c2_wl = (const float*)d_in[11];
    const float* c2_bl = (const float*)d_in[12];
    const float* c2_wr = (const float*)d_in[13];
    const float* lin_w = (const float*)d_in[14];
    const float* lin_b = (const float*)d_in[15];
    float* ws  = (float*)d_ws;
    float* out = (float*)d_out;

    prep_x0<<<(N0 + 255) / 256, 256, 0, stream>>>(x0, ws);
    sage1_scatter<<<(E0 + 255) / 256, 256, 0, stream>>>(x0, e0, ws);
    sage1_finish<<<(N0 + 255) / 256, 256, 0, stream>>>(x0, c1_wl, c1_bl, c1_wr, ws);
    main_kernel<<<NT / 64, 256, 0, stream>>>(x, x0, emb_w, fc_w, fc_b, fc2_w, fc2_b,
                                             c1_wr, c1_bl, c2_wl, c2_bl, c2_wr,
                                             lin_w, lin_b, ws, out);
}

// Round 6
// 213.430 us; speedup vs baseline: 2.5879x; 1.6824x over previous
//
#include <hip/hip_runtime.h>
#include <math.h>

#define N0 3190
#define NT 32768
#define E0 51040
#define CH 256   // x0 rows per LDS chunk (36.9KB block LDS -> 4 blocks/CU)

// ws layout (floats):
// [0,N0)        n0
// [N0,2N0)      rn0 = 1/n0
// [2N0,12N0)    agg (N0*10)
// [12N0,13N0)   cnt
// [13N0,28N0)   o1_0 (N0*15)

__global__ void prep_x0(const float* __restrict__ x0, float* __restrict__ ws) {
    int i = blockIdx.x * 256 + threadIdx.x;
    if (i >= N0) return;
    float s = 0.f;
#pragma unroll
    for (int c = 0; c < 10; ++c) { float v = x0[i * 10 + c]; s = fmaf(v, v, s); }
    float n = sqrtf(s);
    ws[i] = n;
    ws[N0 + i] = 1.0f / n;
#pragma unroll
    for (int c = 0; c < 10; ++c) ws[2 * N0 + i * 10 + c] = 0.f;
    ws[12 * N0 + i] = 0.f;
}

__global__ void sage1_scatter(const float* __restrict__ x0, const int* __restrict__ e0,
                              float* __restrict__ ws) {
    int e = blockIdx.x * 256 + threadIdx.x;
    if (e >= E0) return;
    int s = e0[e];
    int d = e0[E0 + e];
    float* agg = ws + 2 * N0;
#pragma unroll
    for (int c = 0; c < 10; ++c) atomicAdd(&agg[d * 10 + c], x0[s * 10 + c]);
    atomicAdd(&ws[12 * N0 + d], 1.0f);
}

__global__ void sage1_finish(const float* __restrict__ x0,
                             const float* __restrict__ c1_wl, const float* __restrict__ c1_bl,
                             const float* __restrict__ c1_wr, float* __restrict__ ws) {
    int i = blockIdx.x * 256 + threadIdx.x;
    if (i >= N0) return;
    const float* agg = ws + 2 * N0 + i * 10;
    float den = fmaxf(ws[12 * N0 + i], 1.0f);
    float m[10], xr[10];
#pragma unroll
    for (int c = 0; c < 10; ++c) { m[c] = agg[c] / den; xr[c] = x0[i * 10 + c]; }
    float* o = ws + 13 * N0 + i * 15;
#pragma unroll
    for (int k = 0; k < 15; ++k) {
        float s = c1_bl[k];
#pragma unroll
        for (int c = 0; c < 10; ++c) s = fmaf(m[c], c1_wl[k * 10 + c], s);
#pragma unroll
        for (int c = 0; c < 10; ++c) s = fmaf(xr[c], c1_wr[k * 10 + c], s);
        o[k] = fmaxf(s, 0.f);
    }
}

#define BETTER(k, j, v, i) ((k) > (v) || ((k) == (v) && (j) < (i)))

__launch_bounds__(256)
__global__ void main_kernel(const float* __restrict__ x, const float* __restrict__ x0,
                            const float* __restrict__ emb_w, const float* __restrict__ fc_w,
                            const float* __restrict__ fc_b, const float* __restrict__ fc2_w,
                            const float* __restrict__ fc2_b,
                            const float* __restrict__ c1_wr, const float* __restrict__ c1_bl,
                            const float* __restrict__ c2_wl, const float* __restrict__ c2_bl,
                            const float* __restrict__ c2_wr,
                            const float* __restrict__ lin_w, const float* __restrict__ lin_b,
                            const float* __restrict__ ws, float* __restrict__ out) {
    __shared__ float s_emb[25], s_fcw[1200], s_fcb[20], s_fc2w[1000], s_fc2b[10];
    __shared__ float s_c1wr[150], s_c1bl[15], s_c2wl[150], s_c2bl[10], s_c2wr[150];
    __shared__ float s_linw[30], s_linb[3];
    __shared__ __align__(16) float s_x0[CH * 12];
    __shared__ float s_rn0[CH];
    __shared__ float s_mv[64 * 24];
    __shared__ int   s_mi[64 * 24];

    const int tid = threadIdx.x;
    for (int i = tid; i < 25;   i += 256) s_emb[i]  = emb_w[i];
    for (int i = tid; i < 1200; i += 256) s_fcw[i]  = fc_w[i];
    for (int i = tid; i < 20;   i += 256) s_fcb[i]  = fc_b[i];
    for (int i = tid; i < 1000; i += 256) s_fc2w[i] = fc2_w[i];
    for (int i = tid; i < 10;   i += 256) s_fc2b[i] = fc2_b[i];
    for (int i = tid; i < 150;  i += 256) s_c1wr[i] = c1_wr[i];
    for (int i = tid; i < 15;   i += 256) s_c1bl[i] = c1_bl[i];
    for (int i = tid; i < 150;  i += 256) s_c2wl[i] = c2_wl[i];
    for (int i = tid; i < 10;   i += 256) s_c2bl[i] = c2_bl[i];
    for (int i = tid; i < 150;  i += 256) s_c2wr[i] = c2_wr[i];
    for (int i = tid; i < 30;   i += 256) s_linw[i] = lin_w[i];
    for (int i = tid; i < 3;    i += 256) s_linb[i] = lin_b[i];
    __syncthreads();

    const int node = blockIdx.x * 64 + (tid >> 2);
    const int q = tid & 3;

    // ---------- encoder (k-quarter per lane) ----------
    float acc[5][5];   // [e][kl], k = 5*q+kl
#pragma unroll
    for (int e = 0; e < 5; ++e)
#pragma unroll
        for (int kl = 0; kl < 5; ++kl) acc[e][kl] = 0.f;

    const float* xp = x + (size_t)node * 5;
    for (int f = 0; f < 60; ++f) {
        float xin[5];
#pragma unroll
        for (int c = 0; c < 5; ++c) xin[c] = xp[(size_t)f * NT * 5 + c];
        float hm[5];
#pragma unroll
        for (int e = 0; e < 5; ++e) {
            float s = 0.f;
#pragma unroll
            for (int c = 0; c < 5; ++c) s = fmaf(xin[c], s_emb[c * 5 + e], s);
            hm[e] = fmaxf(s, 0.f);
        }
#pragma unroll
        for (int kl = 0; kl < 5; ++kl) {
            float w = s_fcw[(5 * q + kl) * 60 + f];
#pragma unroll
            for (int e = 0; e < 5; ++e) acc[e][kl] = fmaf(hm[e], w, acc[e][kl]);
        }
    }

    float hp[10];
#pragma unroll
    for (int u = 0; u < 10; ++u) hp[u] = 0.f;
#pragma unroll
    for (int kl = 0; kl < 5; ++kl) {
        const int k = 5 * q + kl;
#pragma unroll
        for (int e = 0; e < 5; ++e) {
            float z = fmaxf(acc[e][kl] + s_fcb[k], 0.f);
            const int zi = k * 5 + e;
#pragma unroll
            for (int u = 0; u < 10; ++u) hp[u] = fmaf(s_fc2w[u * 100 + zi], z, hp[u]);
        }
    }
#pragma unroll
    for (int u = 0; u < 10; ++u) {
        hp[u] += __shfl_xor(hp[u], 1);
        hp[u] += __shfl_xor(hp[u], 2);
    }
    float h[10];
#pragma unroll
    for (int u = 0; u < 10; ++u) h[u] = fmaxf(hp[u] + s_fc2b[u], 0.f);

    float nh2 = 0.f;
#pragma unroll
    for (int u = 0; u < 10; ++u) nh2 = fmaf(h[u], h[u], nh2);
    const float nh = sqrtf(nh2);

    // SAGE1 at test node: no incoming edge_0 edges -> agg=0
    float o1t[15];
#pragma unroll
    for (int k = 0; k < 15; ++k) {
        float s = s_c1bl[k];
#pragma unroll
        for (int u = 0; u < 10; ++u) s = fmaf(h[u], s_c1wr[k * 10 + u], s);
        o1t[k] = fmaxf(s, 0.f);
    }

    // ---------- cosine top-6 (stable), j strided by quad lane ----------
    float v0 = -INFINITY, v1 = -INFINITY, v2 = -INFINITY, v3 = -INFINITY, v4 = -INFINITY, v5 = -INFINITY;
    int i0 = 0, i1 = 0, i2 = 0, i3 = 0, i4 = 0, i5 = 0;

    for (int c0 = 0; c0 < N0; c0 += CH) {
        const int cn = min(CH, N0 - c0);
        __syncthreads();
        for (int idx = tid; idx < cn * 10; idx += 256) {
            int r = idx / 10;
            int cc = idx - r * 10;
            s_x0[r * 12 + cc] = x0[(size_t)(c0 + r) * 10 + cc];
        }
        for (int idx = tid; idx < cn; idx += 256) s_rn0[idx] = ws[N0 + c0 + idx];
        __syncthreads();
        for (int j = q; j < cn; j += 4) {
            const float* r = &s_x0[j * 12];
            float4 p0 = *(const float4*)r;
            float4 p1 = *(const float4*)(r + 4);
            float2 p2 = *(const float2*)(r + 8);
            float dot = 0.f;
            dot = fmaf(h[0], p0.x, dot); dot = fmaf(h[1], p0.y, dot); dot = fmaf(h[2], p0.z, dot); dot = fmaf(h[3], p0.w, dot);
            dot = fmaf(h[4], p1.x, dot); dot = fmaf(h[5], p1.y, dot); dot = fmaf(h[6], p1.z, dot); dot = fmaf(h[7], p1.w, dot);
            dot = fmaf(h[8], p2.x, dot); dot = fmaf(h[9], p2.y, dot);
            float key = dot * s_rn0[j];
            if (key > v5) {
                int jj = c0 + j;
                if (key > v4) { v5 = v4; i5 = i4;
                    if (key > v3) { v4 = v3; i4 = i3;
                        if (key > v2) { v3 = v2; i3 = i2;
                            if (key > v1) { v2 = v1; i2 = i1;
                                if (key > v0) { v1 = v0; i1 = i0; v0 = key; i0 = jj; }
                                else { v1 = key; i1 = jj; }
                            } else { v2 = key; i2 = jj; }
                        } else { v3 = key; i3 = jj; }
                    } else { v4 = key; i4 = jj; }
                } else { v5 = key; i5 = jj; }
            }
        }
    }

    // ---------- merge 4 lanes' top-6 -> global stable top-6 ----------
    const int nl = tid >> 2;
    {
        int b = nl * 24 + q * 6;
        s_mv[b + 0] = v0; s_mi[b + 0] = i0;
        s_mv[b + 1] = v1; s_mi[b + 1] = i1;
        s_mv[b + 2] = v2; s_mi[b + 2] = i2;
        s_mv[b + 3] = v3; s_mi[b + 3] = i3;
        s_mv[b + 4] = v4; s_mi[b + 4] = i4;
        s_mv[b + 5] = v5; s_mi[b + 5] = i5;
    }
    __syncthreads();

    if (q == 0) {
        float m0 = -INFINITY, m1 = -INFINITY, m2 = -INFINITY, m3 = -INFINITY, m4 = -INFINITY, m5 = -INFINITY;
        int j0 = 0, j1 = 0, j2 = 0, j3 = 0, j4 = 0, j5 = 0;
        for (int s = 0; s < 24; ++s) {
            float kv = s_mv[nl * 24 + s];
            int ki = s_mi[nl * 24 + s];
            if (BETTER(kv, ki, m5, j5)) {
                if (BETTER(kv, ki, m4, j4)) { m5 = m4; j5 = j4;
                    if (BETTER(kv, ki, m3, j3)) { m4 = m3; j4 = j3;
                        if (BETTER(kv, ki, m2, j2)) { m3 = m2; j3 = j2;
                            if (BETTER(kv, ki, m1, j1)) { m2 = m1; j2 = j1;
                                if (BETTER(kv, ki, m0, j0)) { m1 = m0; j1 = j0; m0 = kv; j0 = ki; }
                                else { m1 = kv; j1 = ki; }
                            } else { m2 = kv; j2 = ki; }
                        } else { m3 = kv; j3 = ki; }
                    } else { m4 = kv; j4 = ki; }
                } else { m5 = kv; j5 = ki; }
            }
        }

        // selfmatch: recompute exact a = (dot/nh)/n0 for the top entry
        float dot0 = 0.f;
        const float* xr = x0 + (size_t)j0 * 10;
#pragma unroll
        for (int c = 0; c < 10; ++c) dot0 = fmaf(h[c], xr[c], dot0);
        float a0 = (dot0 / nh) / ws[j0];
        bool selfm = (a0 == 1.0f);
        int n1 = selfm ? j1 : j0;
        int n2 = selfm ? j2 : j1;
        int n3 = selfm ? j3 : j2;
        int n4 = selfm ? j4 : j3;
        int n5 = selfm ? j5 : j4;

        const float* o10 = ws + 13 * N0;
        float mean[15];
#pragma unroll
        for (int k = 0; k < 15; ++k) {
            float s = o10[(size_t)n1 * 15 + k];
            s += o10[(size_t)n2 * 15 + k];
            s += o10[(size_t)n3 * 15 + k];
            s += o10[(size_t)n4 * 15 + k];
            s += o10[(size_t)n5 * 15 + k];
            mean[k] = s / 5.0f;
        }

        float o2[10];
#pragma unroll
        for (int u = 0; u < 10; ++u) {
            float s = s_c2bl[u];
#pragma unroll
            for (int k = 0; k < 15; ++k) s = fmaf(mean[k], s_c2wl[u * 15 + k], s);
#pragma unroll
            for (int k = 0; k < 15; ++k) s = fmaf(o1t[k], s_c2wr[u * 15 + k], s);
            o2[u] = s;
        }

        float l0 = s_linb[0], l1 = s_linb[1], l2 = s_linb[2];
#pragma unroll
        for (int u = 0; u < 10; ++u) {
            l0 = fmaf(o2[u], s_linw[u], l0);
            l1 = fmaf(o2[u], s_linw[10 + u], l1);
            l2 = fmaf(o2[u], s_linw[20 + u], l2);
        }
        float mx = fmaxf(l0, fmaxf(l1, l2));
        float e0 = expf(l0 - mx), e1 = expf(l1 - mx), e2 = expf(l2 - mx);
        float sum = e0 + e1 + e2;
        out[(size_t)node * 3 + 0] = e0 / sum;
        out[(size_t)node * 3 + 1] = e1 / sum;
        out[(size_t)node * 3 + 2] = e2 / sum;
    }
}

extern "C" void kernel_launch(void* const* d_in, const int* in_sizes, int n_in,
                              void* d_out, int out_size, void* d_ws, size_t ws_size,
                              hipStream_t stream) {
    const float* x     = (const float*)d_in[0];
    const float* x0    = (const float*)d_in[1];
    const int*   e0    = (const int*)d_in[2];
    const float* emb_w = (const float*)d_in[3];
    const float* fc_w  = (const float*)d_in[4];
    const float* fc_b  = (const float*)d_in[5];
    const float* fc2_w = (const float*)d_in[6];
    const float* fc2_b = (const float*)d_in[7];
    const float* c1_wl = (const float*)d_in[8];
    const float* c1_bl = (const float*)d_in[9];
    const float* c1_wr = (const float*)d_in[10];
    const float* c2_wl = (const float*)d_in[11];
    const float* c2_bl = (const float*)d_in[12];
    const float* c2_wr = (const float*)d_in[13];
    const float* lin_w = (const float*)d_in[14];
    const float* lin_b = (const float*)d_in[15];
    float* ws  = (float*)d_ws;
    float* out = (float*)d_out;

    prep_x0<<<(N0 + 255) / 256, 256, 0, stream>>>(x0, ws);
    sage1_scatter<<<(E0 + 255) / 256, 256, 0, stream>>>(x0, e0, ws);
    sage1_finish<<<(N0 + 255) / 256, 256, 0, stream>>>(x0, c1_wl, c1_bl, c1_wr, ws);
    main_kernel<<<NT / 64, 256, 0, stream>>>(x, x0, emb_w, fc_w, fc_b, fc2_w, fc2_b,
                                             c1_wr, c1_bl, c2_wl, c2_bl, c2_wr,
                                             lin_w, lin_b, ws, out);
}